// Round 8
// baseline (104.305 us; speedup 1.0000x reference)
//
#include <hip/hip_runtime.h>
#include <math.h>

#define QN 4096
#define NN 1024
#define FD 64
#define HD 128

typedef float v2f __attribute__((ext_vector_type(2)));

// workspace layout (float offsets)
#define OFF_UB    0                      // UB [16 qblk][64 h2][4 qq][64 lane][2]
#define OFF_B     524288                 // B   [1024 n][128 h]
#define OFF_VU    655360                 // vu  [4096 q]
#define OFF_VB    659456                 // vb  [1024 n]
#define OFF_L     660480                 // L   [1024 n][4096 q]
#define OFF_PM    4854784                // pm  [64 tile][4096 q]
#define OFF_PART  5116928                // part[8 c][4096 q][64 f]
#define OFF_SPART 7214080                // spart[8 c][4096 q]
// end: 7246848 floats = 29.0 MB

// ---------------- K0: fused prep: UB, B, vb, vu ----------------
__global__ __launch_bounds__(256) void k0_prep(
    const float* __restrict__ qp, const float* __restrict__ nf,
    const float* __restrict__ npos, const float* __restrict__ aW1,
    const float* __restrict__ ab1, const float* __restrict__ aW2,
    float* __restrict__ B, float* __restrict__ UB,
    float* __restrict__ vu, float* __restrict__ vb) {
  int bid = blockIdx.x, t = threadIdx.x;
  if (bid < 2048) {
    // UB flat = qblk*32768 + h2*512 + qq*128 + lane*2 + e
    int idx = bid * 256 + t;
    int e = idx & 1, lane = (idx >> 1) & 63, qq = (idx >> 7) & 3;
    int h2 = (idx >> 9) & 63, qblk = idx >> 15;
    int q = qblk * 256 + qq * 64 + lane;
    int h = h2 * 2 + e;
    float u = qp[q*3+0] * aW1[(FD+0)*HD + h]
            + qp[q*3+1] * aW1[(FD+1)*HD + h]
            + qp[q*3+2] * aW1[(FD+2)*HD + h];
    UB[idx] = u;
  } else if (bid < 2560) {
    int i2 = (bid - 2048) * 256 + t;
    int n = i2 >> 7, h = i2 & 127;
    float s = ab1[h];
    #pragma unroll
    for (int f = 0; f < FD; ++f) s = fmaf(nf[n*FD+f], aW1[f*HD+h], s);
    s -= npos[n*3+0] * aW1[(FD+0)*HD + h]
       + npos[n*3+1] * aW1[(FD+1)*HD + h]
       + npos[n*3+2] * aW1[(FD+2)*HD + h];
    B[i2] = s;
    float pv = s * aW2[h];
    #pragma unroll
    for (int m = 1; m < 64; m <<= 1) pv += __shfl_xor(pv, m, 64);
    __shared__ float ps[4];
    if ((t & 63) == 0) ps[t >> 6] = pv;
    __syncthreads();
    if (t == 0)   vb[n] = ps[0] + ps[1];
    if (t == 128) vb[n] = ps[2] + ps[3];
  } else {
    int q = (bid - 2560) * 256 + t;
    float q0 = qp[q*3+0], q1 = qp[q*3+1], q2 = qp[q*3+2];
    float acc = 0.f;
    #pragma unroll
    for (int h = 0; h < HD; ++h) {
      float u = q0 * aW1[(FD+0)*HD + h]
              + q1 * aW1[(FD+1)*HD + h]
              + q2 * aW1[(FD+2)*HD + h];
      acc = fmaf(aW2[h], u, acc);
    }
    vu[q] = acc;
  }
}

// ---------------- K2: logits v3 ----------------
// tile 256q x 16n; 4 q/lane; wave w -> n-slice [w*4, w*4+4)
// U via imm-offset dwordx2 off 2 bumped ptrs; B via imm-offset ds_read_b64.

#define LOADU(dst) { \
  _Pragma("unroll") for (int qq = 0; qq < 4; ++qq) { \
    dst[qq][0] = P0[qq*64]; \
    dst[qq][1] = P0[qq*64 + 256]; \
    dst[qq][2] = P1[qq*64]; \
    dst[qq][3] = P1[qq*64 + 256]; } \
  P0 += 1024; P1 += 1024; }

#define COMPUTE(u) { \
  float aw0 = aw[0], aw1 = aw[1], aw2 = aw[2], aw3 = aw[3]; \
  float aw4 = aw[4], aw5 = aw[5], aw6 = aw[6], aw7 = aw[7]; \
  _Pragma("unroll") for (int nn = 0; nn < 4; ++nn) { \
    v2f b0 = bsB[nn*64], b1 = bsB[nn*64 + 1]; \
    v2f b2 = bsB[nn*64 + 2], b3 = bsB[nn*64 + 3]; \
    _Pragma("unroll") for (int qq = 0; qq < 4; ++qq) { \
      v2f t0 = u[qq][0] + b0; \
      v2f t1 = u[qq][1] + b1; \
      v2f t2 = u[qq][2] + b2; \
      v2f t3 = u[qq][3] + b3; \
      float a = acc[qq][nn]; \
      a = fmaf(aw0, __builtin_fabsf(t0.x), a); \
      a = fmaf(aw1, __builtin_fabsf(t0.y), a); \
      a = fmaf(aw2, __builtin_fabsf(t1.x), a); \
      a = fmaf(aw3, __builtin_fabsf(t1.y), a); \
      a = fmaf(aw4, __builtin_fabsf(t2.x), a); \
      a = fmaf(aw5, __builtin_fabsf(t2.y), a); \
      a = fmaf(aw6, __builtin_fabsf(t3.x), a); \
      a = fmaf(aw7, __builtin_fabsf(t3.y), a); \
      acc[qq][nn] = a; } } \
  bsB += 4; aw += 8; }

__global__ __launch_bounds__(256) void k2_logits(
    const float* __restrict__ Bg, const float* __restrict__ UB,
    const float* __restrict__ aW2, const float* __restrict__ ab2,
    const float* __restrict__ qp, const float* __restrict__ npos,
    const float* __restrict__ vu, const float* __restrict__ vb,
    float* __restrict__ L, float* __restrict__ pm) {
  __shared__ float Bs[16 * HD];      // 8 KB
  __shared__ float red[4][4][64];    // 4 KB
  const int q0 = blockIdx.x * 256, n0 = blockIdx.y * 16;
  const int t = threadIdx.x;
  {
    const float4* src = (const float4*)(Bg + n0 * HD);
    float4* dst = (float4*)Bs;
    #pragma unroll
    for (int r = 0; r < 2; ++r) dst[r*256 + t] = src[r*256 + t];
  }
  __syncthreads();
  const int lane = t & 63, w = t >> 6;
  const int nb = w * 4;

  float acc[4][4];
  #pragma unroll
  for (int qq = 0; qq < 4; ++qq)
    #pragma unroll
    for (int nn = 0; nn < 4; ++nn) acc[qq][nn] = 0.f;

  const v2f* P0 = (const v2f*)UB + (size_t)blockIdx.x * 16384 + lane;
  const v2f* P1 = P0 + 512;
  const v2f* bsB = (const v2f*)Bs + nb * 64;
  const float* aw = aW2;

  v2f uA[4][4], uB4[4][4];
  LOADU(uA);
  #pragma unroll 1
  for (int hc = 0; hc < 14; hc += 2) {
    LOADU(uB4);
    COMPUTE(uA);
    LOADU(uA);
    COMPUTE(uB4);
  }
  LOADU(uB4);
  COMPUTE(uA);
  COMPUTE(uB4);

  const float bias2 = ab2[0];
  float qx[4], qy[4], vuq[4], m4[4];
  #pragma unroll
  for (int qq = 0; qq < 4; ++qq) {
    int q = q0 + qq*64 + lane;
    qx[qq] = qp[q*3+0];
    qy[qq] = qp[q*3+1];
    vuq[qq] = vu[q];
    m4[qq] = -3.4e38f;
  }
  #pragma unroll
  for (int nn = 0; nn < 4; ++nn) {
    int n = n0 + nb + nn;
    float px = npos[n*3+0], py = npos[n*3+1];
    float vbn = vb[n];
    #pragma unroll
    for (int qq = 0; qq < 4; ++qq) {
      float dx = qx[qq] - px, dy = qy[qq] - py;
      float wgt = 1.f / (sqrtf(dx*dx + dy*dy) + 1e-6f);
      float score = fmaf(0.5f, vuq[qq] + vbn + acc[qq][nn], bias2);
      float lg = score * wgt;
      L[n * QN + q0 + qq*64 + lane] = lg;
      m4[qq] = fmaxf(m4[qq], lg);
    }
  }
  #pragma unroll
  for (int qq = 0; qq < 4; ++qq) red[w][qq][lane] = m4[qq];
  __syncthreads();
  {
    int qq = t >> 6, ll = t & 63;
    float mm = fmaxf(fmaxf(red[0][qq][ll], red[1][qq][ll]),
                     fmaxf(red[2][qq][ll], red[3][qq][ll]));
    pm[blockIdx.y * QN + q0 + qq*64 + ll] = mm;
  }
}

// ---------------- K4: exp + partial aggregate v2 ----------------
// 1024 blocks = 128 qt x 8 c; lane: qi=lane&31 (q), fh=lane>>5 (f-half)
__global__ __launch_bounds__(256) void k4_agg(
    const float* __restrict__ L, const float* __restrict__ pm,
    const float* __restrict__ nf, float* __restrict__ part,
    float* __restrict__ spart) {
  __shared__ float red[4][2][32][33];   // 33.8 KB, padded
  __shared__ float sred[4][33];
  int b = blockIdx.x;
  int qt = b & 127, c = b >> 7;        // c in [0,8)
  int t = threadIdx.x, lane = t & 63, w = t >> 6;
  int qi = lane & 31, fh = lane >> 5;
  int q = qt * 32 + qi;

  float m = -3.4e38f;
  #pragma unroll
  for (int k = 0; k < 64; ++k) m = fmaxf(m, pm[k * QN + q]);

  float acc[32];
  #pragma unroll
  for (int f = 0; f < 32; ++f) acc[f] = 0.f;
  float s = 0.f;

  int nbase = c * 128 + w * 32;
  const float* Lp = L + (size_t)nbase * QN + q;
  float cur = *Lp;
  for (int i = 0; i < 32; ++i) {
    float nxt = (i < 31) ? Lp[(size_t)(i + 1) * QN] : 0.f;
    float p = exp2f((cur - m) * 1.44269504088896f);
    s += p;
    const float4* nfr = (const float4*)(nf + (nbase + i) * FD + fh * 32);
    #pragma unroll
    for (int g = 0; g < 8; ++g) {
      float4 a = nfr[g];
      acc[g*4+0] = fmaf(p, a.x, acc[g*4+0]);
      acc[g*4+1] = fmaf(p, a.y, acc[g*4+1]);
      acc[g*4+2] = fmaf(p, a.z, acc[g*4+2]);
      acc[g*4+3] = fmaf(p, a.w, acc[g*4+3]);
    }
    cur = nxt;
  }

  #pragma unroll
  for (int fi = 0; fi < 32; ++fi) red[w][fh][fi][qi] = acc[fi];
  if (fh == 0) sred[w][qi] = s;
  __syncthreads();
  #pragma unroll
  for (int k = 0; k < 8; ++k) {
    int idx = k * 256 + t;
    int qq = idx >> 6, f = idx & 63;
    int f1 = f >> 5, f0 = f & 31;
    float sum = red[0][f1][f0][qq] + red[1][f1][f0][qq]
              + red[2][f1][f0][qq] + red[3][f1][f0][qq];
    part[((size_t)c * QN + qt*32 + qq) * 64 + f] = sum;
  }
  if (t < 32) {
    spart[c * QN + qt*32 + t] = sred[0][t] + sred[1][t] + sred[2][t] + sred[3][t];
  }
}

// ---------------- K5: reduce partials, normalize, decode ----------------
__global__ __launch_bounds__(256) void k5_dec(
    const float* __restrict__ part, const float* __restrict__ spart,
    const float* __restrict__ dW1, const float* __restrict__ db1,
    const float* __restrict__ dW2, const float* __restrict__ db2,
    float* __restrict__ out) {
  __shared__ float agg[16][64];
  __shared__ float inv[16];
  __shared__ float h1s[16][128];
  int t = threadIdx.x;
  int qb = blockIdx.x * 16;
  if (t < 16) {
    float s = 0.f;
    #pragma unroll
    for (int c = 0; c < 8; ++c) s += spart[c*QN + qb + t];
    inv[t] = 1.f / s;
  }
  {
    int f = t & 63, qh = t >> 6;
    #pragma unroll
    for (int pass = 0; pass < 4; ++pass) {
      int qs = pass*4 + qh;
      float v = 0.f;
      #pragma unroll
      for (int c = 0; c < 8; ++c) v += part[((size_t)c*QN + qb + qs)*64 + f];
      agg[qs][f] = v;
    }
  }
  __syncthreads();
  {
    int h = t & 127, qg = t >> 7;
    #pragma unroll
    for (int k = 0; k < 8; ++k) {
      int qs = qg*8 + k;
      float a = 0.f;
      #pragma unroll
      for (int f = 0; f < 64; ++f) a = fmaf(agg[qs][f], dW1[f*HD + h], a);
      h1s[qs][h] = fmaxf(a * inv[qs] + db1[h], 0.f);
    }
  }
  __syncthreads();
  if (t < 48) {
    int qs = t / 3, o = t % 3;
    float a = db2[o];
    #pragma unroll
    for (int h = 0; h < HD; ++h) a = fmaf(h1s[qs][h], dW2[h*3 + o], a);
    out[(qb + qs)*3 + o] = a;
  }
}

extern "C" void kernel_launch(void* const* d_in, const int* in_sizes, int n_in,
                              void* d_out, int out_size, void* d_ws, size_t ws_size,
                              hipStream_t stream) {
  const float* qp   = (const float*)d_in[0];
  const float* nf   = (const float*)d_in[1];
  const float* npos = (const float*)d_in[2];
  const float* aW1  = (const float*)d_in[3];
  const float* ab1  = (const float*)d_in[4];
  const float* aW2  = (const float*)d_in[5];
  const float* ab2  = (const float*)d_in[6];
  const float* dW1  = (const float*)d_in[7];
  const float* db1  = (const float*)d_in[8];
  const float* dW2  = (const float*)d_in[9];
  const float* db2  = (const float*)d_in[10];

  float* ws    = (float*)d_ws;
  float* UB    = ws + OFF_UB;
  float* B     = ws + OFF_B;
  float* vu    = ws + OFF_VU;
  float* vb    = ws + OFF_VB;
  float* L     = ws + OFF_L;
  float* pm    = ws + OFF_PM;
  float* part  = ws + OFF_PART;
  float* spart = ws + OFF_SPART;

  hipLaunchKernelGGL(k0_prep, dim3(2576), dim3(256), 0, stream,
                     qp, nf, npos, aW1, ab1, aW2, B, UB, vu, vb);
  hipLaunchKernelGGL(k2_logits, dim3(16, 64), dim3(256), 0, stream,
                     B, UB, aW2, ab2, qp, npos, vu, vb, L, pm);
  hipLaunchKernelGGL(k4_agg, dim3(1024), dim3(256), 0, stream, L, pm, nf, part, spart);
  hipLaunchKernelGGL(k5_dec, dim3(256), dim3(256), 0, stream,
                     part, spart, dW1, db1, dW2, db2, (float*)d_out);
}